// Round 16
// baseline (728.742 us; speedup 1.0000x reference)
//
#include <hip/hip_runtime.h>
#include <hip/hip_bf16.h>
#include <math.h>

#define TT   2048
#define HID  1024
#define NHEAD 8
#define NKVH  2
#define HD   128
#define QKVN 1536
#define NEXP 64
#define NTOP 6
#define I_T  512
#define I_V  256
#define I_S  1024
#define SBASE ((size_t)12288 * 512)   // ACT elem offset of shared region
#define NCHUNK 576                    // sum over qb of ceil(((qb>>1)+1)/8)

typedef unsigned short u16;
typedef __attribute__((ext_vector_type(8))) short short8v;
typedef __attribute__((ext_vector_type(4))) float f32x4;

__device__ inline u16 f2bf(float f) {
  __hip_bfloat16 h = __float2bfloat16(f);
  return *reinterpret_cast<u16*>(&h);
}
__device__ inline float bfu2f(u16 u) {
  unsigned x = ((unsigned)u) << 16;
  return __uint_as_float(x);
}
__device__ inline void split2(float f, u16& h, u16& l) {
  h = f2bf(f);
  l = f2bf(f - bfu2f(h));
}
__device__ inline void split8(const float* f, u16* h, u16* l) {
#pragma unroll
  for (int i = 0; i < 8; ++i) split2(f[i], h[i], l[i]);
}

__device__ inline f32x4 mfma16(short8v a, short8v b, f32x4 c) {
  return __builtin_amdgcn_mfma_f32_16x16x32_bf16(a, b, c, 0, 0, 0);
}

// ---- 64-col weight-chunk staging: 128 k-rows x 64 cols, fp32 -> bf16 LDS
// LDS layout (k-packed-8): elem(k,c) at ((k>>3)*64 + c)*8 + (k&7)
__device__ inline void wload64(const float* __restrict__ W, int ldw, int c0, int kc,
                               float4* r) {
  const int t = threadIdx.x;
  const int c4 = (t & 15) << 2;
  const int r0 = t >> 4;
#pragma unroll
  for (int j = 0; j < 8; ++j)
    r[j] = *(const float4*)&W[(size_t)(kc + r0 + j * 16) * ldw + c0 + c4];
}
__device__ inline void wwrite64(const float4* r, u16* lds) {
  const int t = threadIdx.x;
  const int c4 = (t & 15) << 2;
  const int r0 = t >> 4;
#pragma unroll
  for (int j = 0; j < 8; ++j) {
    int k = r0 + j * 16;
    u16* dst = lds + ((size_t)(k >> 3) * 64 + c4) * 8 + (k & 7);
    float4 v = r[j];
    dst[0]  = f2bf(v.x);
    dst[8]  = f2bf(v.y);
    dst[16] = f2bf(v.z);
    dst[24] = f2bf(v.w);
  }
}
// ---- 128-col weight-chunk staging: 64 k-rows x 128 cols, fp32 -> bf16 LDS
// LDS layout (k-packed-8): elem(k,c) at ((k>>3)*128 + c)*8 + (k&7)
__device__ inline void wload128(const float* __restrict__ W, int ldw, int c0, int kc,
                                float4* r) {
  const int t = threadIdx.x;
  const int c4 = (t & 31) << 2;
  const int r0 = t >> 5;
#pragma unroll
  for (int j = 0; j < 8; ++j)
    r[j] = *(const float4*)&W[(size_t)(kc + r0 + j * 8) * ldw + c0 + c4];
}
__device__ inline void wwrite128(const float4* r, u16* lds) {
  const int t = threadIdx.x;
  const int c4 = (t & 31) << 2;
  const int r0 = t >> 5;
#pragma unroll
  for (int j = 0; j < 8; ++j) {
    int k = r0 + j * 8;
    u16* dst = lds + ((size_t)(k >> 3) * 128 + c4) * 8 + (k & 7);
    float4 v = r[j];
    dst[0]  = f2bf(v.x);
    dst[8]  = f2bf(v.y);
    dst[16] = f2bf(v.z);
    dst[24] = f2bf(v.w);
  }
}
// hi/lo variant for the dense (split-precision) path
__device__ inline void wwrite64hl(const float4* r, u16* ldsH, u16* ldsL) {
  const int t = threadIdx.x;
  const int c4 = (t & 15) << 2;
  const int r0 = t >> 4;
#pragma unroll
  for (int j = 0; j < 8; ++j) {
    int k = r0 + j * 16;
    size_t base = ((size_t)(k >> 3) * 64 + c4) * 8 + (k & 7);
    float4 v = r[j];
    u16 h, l;
    split2(v.x, h, l); ldsH[base]      = h; ldsL[base]      = l;
    split2(v.y, h, l); ldsH[base + 8]  = h; ldsL[base + 8]  = l;
    split2(v.z, h, l); ldsH[base + 16] = h; ldsL[base + 16] = l;
    split2(v.w, h, l); ldsH[base + 24] = h; ldsL[base + 24] = l;
  }
}

// ---------------- RMSNorm (templated outputs: fp32, bf16-hi, bf16-lo) ----------------
template<bool F32, bool BF, bool LO>
__global__ __launch_bounds__(256) void rmsnorm_kernel(const float* __restrict__ x,
                                                      const float* __restrict__ w,
                                                      float* __restrict__ o32,
                                                      u16* __restrict__ obfH,
                                                      u16* __restrict__ obfL) {
  const int row = blockIdx.x;
  const int t = threadIdx.x;
  const float4 v = *(const float4*)(x + (size_t)row * HID + t * 4);
  float ss = v.x*v.x + v.y*v.y + v.z*v.z + v.w*v.w;
#pragma unroll
  for (int m = 32; m >= 1; m >>= 1) ss += __shfl_xor(ss, m);
  __shared__ float red[4];
  __shared__ float rrs;
  if ((t & 63) == 0) red[t >> 6] = ss;
  __syncthreads();
  if (t == 0) rrs = rsqrtf((red[0] + red[1] + red[2] + red[3]) * (1.0f / HID) + 1e-5f);
  __syncthreads();
  const float rr = rrs;
  const float4 wv = *(const float4*)(w + t * 4);
  float o[4];
  o[0] = v.x * wv.x * rr; o[1] = v.y * wv.y * rr;
  o[2] = v.z * wv.z * rr; o[3] = v.w * wv.w * rr;
  if (F32) *(float4*)(o32 + (size_t)row * HID + t * 4) = *(float4*)o;
  if (BF) {
    u16 h[4], l[4];
#pragma unroll
    for (int i = 0; i < 4; ++i) split2(o[i], h[i], l[i]);
    *(uint2*)(obfH + (size_t)row * HID + t * 4) = *(uint2*)h;
    if (LO) *(uint2*)(obfL + (size_t)row * HID + t * 4) = *(uint2*)l;
  }
}

// ---------------- dense streaming split-bf16 GEMM (round-13, passing) ----------------
template<bool RES>
__global__ __launch_bounds__(256) void dense_stream(const u16* __restrict__ AH,
                                                    const u16* __restrict__ AL,
                                                    const float* __restrict__ W,
                                                    const float* __restrict__ resid,
                                                    float* __restrict__ C, int N) {
  __shared__ u16 sWH[8192], sWL[8192];
  const int c0 = blockIdx.x * 64;
  const int m0 = blockIdx.y * 128;
  const int w = threadIdx.x >> 6, lane = threadIdx.x & 63;
  const int lrow = lane & 15, loct = lane >> 4;
  const int rbase = m0 + w * 32;

  f32x4 acc[2][4];
#pragma unroll
  for (int rt = 0; rt < 2; ++rt)
#pragma unroll
    for (int cf = 0; cf < 4; ++cf) acc[rt][cf] = (f32x4){0.f,0.f,0.f,0.f};

  float4 rw[8];
  wload64(W, N, c0, 0, rw);
  wwrite64hl(rw, sWH, sWL);
  __syncthreads();
  for (int c = 0; c < 8; ++c) {
    if (c + 1 < 8) wload64(W, N, c0, (c + 1) * 128, rw);
#pragma unroll
    for (int ks = 0; ks < 4; ++ks) {
      short8v ah[2], al[2];
#pragma unroll
      for (int rt = 0; rt < 2; ++rt) {
        size_t g = (size_t)(rbase + rt * 16 + lrow) * HID + c * 128 + ks * 32 + loct * 8;
        ah[rt] = *(const short8v*)&AH[g];
        al[rt] = *(const short8v*)&AL[g];
      }
      const int gbase = ((ks * 4 + loct) * 64 + lrow) * 8;
#pragma unroll
      for (int cf = 0; cf < 4; ++cf) {
        short8v bh = *(const short8v*)&sWH[gbase + cf * 128];
        short8v bl = *(const short8v*)&sWL[gbase + cf * 128];
#pragma unroll
        for (int rt = 0; rt < 2; ++rt) {
          acc[rt][cf] = mfma16(ah[rt], bh, acc[rt][cf]);
          acc[rt][cf] = mfma16(ah[rt], bl, acc[rt][cf]);
          acc[rt][cf] = mfma16(al[rt], bh, acc[rt][cf]);
          acc[rt][cf] = mfma16(al[rt], bl, acc[rt][cf]);
        }
      }
    }
    __syncthreads();
    if (c + 1 < 8) {
      wwrite64hl(rw, sWH, sWL);
      __syncthreads();
    }
  }
#pragma unroll
  for (int rt = 0; rt < 2; ++rt)
#pragma unroll
    for (int cf = 0; cf < 4; ++cf)
#pragma unroll
      for (int i = 0; i < 4; ++i) {
        int row = rbase + rt * 16 + loct * 4 + i;
        int col = c0 + cf * 16 + lrow;
        float v = acc[rt][cf][i];
        if (RES) v += resid[(size_t)row * N + col];
        C[(size_t)row * N + col] = v;
      }
}

// ---------------- pack_qkv: rope + hi/lo split into MFMA-layout buffers ----------------
// V stored KEY-PERMUTED for swapped-PV A-operand: slot (g,j) holds key (j>>2)*16+g*4+(j&3)
__global__ __launch_bounds__(256) void pack_qkv(const float* __restrict__ qkv,
                                                const int* __restrict__ pos,
                                                u16* __restrict__ Qh, u16* __restrict__ Ql,
                                                u16* __restrict__ Kph, u16* __restrict__ Kpl,
                                                u16* __restrict__ Vph, u16* __restrict__ Vpl) {
  const int tile = blockIdx.x;
  const int t = threadIdx.x;
  __shared__ float cs[2048], sn[2048];   // [tok32][fi]
  for (int i = t; i < 2048; i += 256) {
    int tok32 = i >> 6, fi = i & 63;
    int tok = tile * 32 + tok32;
    int axis = (fi < 22) ? 0 : (fi < 44 ? 1 : 2);
    float posv = (float)pos[axis * TT + tok];
    float invf = powf(500000.0f, -((float)(2 * fi)) / 128.0f);
    float ang = posv * invf;
    sincosf(ang, &sn[i], &cs[i]);
  }
  __syncthreads();
  for (int task = t; task < 4096; task += 256) {
    int h = task >> 9;
    int rem = task & 511;
    int tok32 = rem >> 4, fi4 = rem & 15;
    int tok = tile * 32 + tok32;
    const float* src = qkv + (size_t)tok * QKVN + h * HD + fi4 * 8;
    float4 v0 = *(const float4*)src, v1 = *(const float4*)(src + 4);
    float f[8] = {v0.x, v0.y, v0.z, v0.w, v1.x, v1.y, v1.z, v1.w};
    float o[8];
#pragma unroll
    for (int j = 0; j < 4; ++j) {
      int fi = fi4 * 4 + j;
      float c = cs[tok32 * 64 + fi], s = sn[tok32 * 64 + fi];
      o[2*j]   = f[2*j] * c - f[2*j+1] * s;
      o[2*j+1] = f[2*j] * s + f[2*j+1] * c;
    }
    u16 h8[8], l8[8];
    split8(o, h8, l8);
    size_t d = (size_t)tok * HID + h * HD + fi4 * 8;
    *(uint4*)&Qh[d] = *(uint4*)h8;
    *(uint4*)&Ql[d] = *(uint4*)l8;
  }
  for (int task = t; task < 1024; task += 256) {
    int kvh = task >> 9;
    int rem = task & 511;
    int kk = rem >> 4, fi4 = rem & 15;
    int tok = tile * 32 + kk;
    const float* src = qkv + (size_t)tok * QKVN + NHEAD * HD + kvh * HD + fi4 * 8;
    float4 v0 = *(const float4*)src, v1 = *(const float4*)(src + 4);
    float f[8] = {v0.x, v0.y, v0.z, v0.w, v1.x, v1.y, v1.z, v1.w};
    float o[8];
#pragma unroll
    for (int j = 0; j < 4; ++j) {
      int fi = fi4 * 4 + j;
      float c = cs[kk * 64 + fi], s = sn[kk * 64 + fi];
      o[2*j]   = f[2*j] * c - f[2*j+1] * s;
      o[2*j+1] = f[2*j] * s + f[2*j+1] * c;
    }
    u16 h8[8], l8[8];
    split8(o, h8, l8);
    size_t d = ((size_t)(kvh * 64 + tile) << 12) + (size_t)(fi4 * 32 + kk) * 8;
    *(uint4*)&Kph[d] = *(uint4*)h8;
    *(uint4*)&Kpl[d] = *(uint4*)l8;
  }
  for (int task = t; task < 1024; task += 256) {
    int kvh = task >> 9;
    int rem = task & 511;
    int g = rem >> 7, dcol = rem & 127;
    float f[8];
#pragma unroll
    for (int e = 0; e < 8; ++e) {
      int key = ((e >> 2) * 16) + g * 4 + (e & 3);   // permuted for P-frag match
      f[e] = qkv[(size_t)(tile * 32 + key) * QKVN + (NHEAD + NKVH) * HD + kvh * HD + dcol];
    }
    u16 h8[8], l8[8];
    split8(f, h8, l8);
    size_t d = ((size_t)(kvh * 64 + tile) << 12) + (size_t)(g * 128 + dcol) * 8;
    *(uint4*)&Vph[d] = *(uint4*)h8;
    *(uint4*)&Vpl[d] = *(uint4*)l8;
  }
}

// ---------------- chunk table setup (parallel, closed-form startOff) ----------------
__global__ void chunk_setup(int* __restrict__ tab, int* __restrict__ startOff) {
  const int qb = threadIdx.x;
  if (qb < TT / 16) {
    const int g = qb >> 4, r = qb & 15;
    const int s0 = qb + 16 * (g * (g - 1) / 2) + r * g;  // sum_{q<qb} ((q>>4)+1)
    startOff[qb] = s0;
    const int nch = g + 1;                                // ceil(((qb>>1)+1)/8)
    for (int c = 0; c < nch; ++c) tab[s0 + c] = qb * 16 + c;
  }
}

// ---------------- attention partial, SWAPPED QK^T (round-10, passing) ----------------
__global__ __launch_bounds__(256) void attn_part(const u16* __restrict__ Qh,
                                                 const u16* __restrict__ Ql,
                                                 const u16* __restrict__ Kph,
                                                 const u16* __restrict__ Kpl,
                                                 const u16* __restrict__ Vph,
                                                 const u16* __restrict__ Vpl,
                                                 const int* __restrict__ tab,
                                                 float* __restrict__ Opart,
                                                 float* __restrict__ Mpart,
                                                 float* __restrict__ Lpart) {
  const int ci = blockIdx.x;
  const int kvh = blockIdx.y;
  const int w = threadIdx.x >> 6, lane = threadIdx.x & 63;
  const int head = kvh * 4 + w;
  const int ent = tab[ci];
  const int qb = ent >> 4, cc = ent & 15;
  const int qw0 = qb * 16;
  const int lrow = lane & 15, loct = lane >> 4;
  const int nkt = (qb >> 1) + 1;
  const int kt0 = cc * 8, kt1 = min(kt0 + 8, nkt);

  short8v qh[4], ql[4];
  {
    const size_t qoff = (size_t)(qw0 + lrow) * HID + head * HD + loct * 8;
#pragma unroll
    for (int dc = 0; dc < 4; ++dc) {
      qh[dc] = *(const short8v*)&Qh[qoff + dc * 32];
      ql[dc] = *(const short8v*)&Ql[qoff + dc * 32];
    }
  }

  f32x4 o[8];
#pragma unroll
  for (int dt = 0; dt < 8; ++dt) o[dt] = (f32x4){0.f,0.f,0.f,0.f};
  float mr = -INFINITY, lr = 0.f;
  const float scale = 0.08838834764831845f;

  for (int kt = kt0; kt < kt1; ++kt) {
    const int kv0 = kt * 32;
    const size_t tb = ((size_t)(kvh * 64 + kt) << 12);
    const u16* kbh = Kph + tb;
    const u16* kbl = Kpl + tb;
    f32x4 s[2];
    __builtin_amdgcn_s_setprio(1);
#pragma unroll
    for (int nt = 0; nt < 2; ++nt) {
      f32x4 shh = {0.f,0.f,0.f,0.f}, shl = {0.f,0.f,0.f,0.f};
      f32x4 slh = {0.f,0.f,0.f,0.f};
#pragma unroll
      for (int dc = 0; dc < 4; ++dc) {
        int off = ((dc * 4 + loct) * 32 + nt * 16 + lrow) * 8;
        short8v kh = *(const short8v*)&kbh[off];
        short8v kl = *(const short8v*)&kbl[off];
        shh = mfma16(kh, qh[dc], shh);
        shl = mfma16(kh, ql[dc], shl);
        slh = mfma16(kl, qh[dc], slh);
      }
      s[nt] = shh + (shl + slh);
    }
    __builtin_amdgcn_s_setprio(0);
    const int qrow = qw0 + lrow;
    float rmax = -INFINITY;
#pragma unroll
    for (int nt = 0; nt < 2; ++nt)
#pragma unroll
      for (int i = 0; i < 4; ++i) {
        int key = kv0 + nt * 16 + loct * 4 + i;
        float v = s[nt][i] * scale;
        s[nt][i] = (key <= qrow) ? v : -INFINITY;
        rmax = fmaxf(rmax, s[nt][i]);
      }
    rmax = fmaxf(rmax, __shfl_xor(rmax, 16));
    rmax = fmaxf(rmax, __shfl_xor(rmax, 32));
    const float mn = fmaxf(mr, rmax);
    const float corr = expf(mr - mn);
    mr = mn;
    float p[2][4];
    float ps = 0.f;
#pragma unroll
    for (int nt = 0; nt < 2; ++nt)
#pragma unroll
      for (int i = 0; i < 4; ++i) { p[nt][i] = expf(s[nt][i] - mr); ps += p[nt][i]; }
    ps += __shfl_xor(ps, 16);
    ps += __shfl_xor(ps, 32);
    lr = lr * corr + ps;
#pragma unroll
    for (int dt = 0; dt < 8; ++dt)
#pragma unroll
      for (int i = 0; i < 4; ++i) o[dt][i] *= corr;
    u16 ph8[8], pl8[8];
#pragma unroll
    for (int j = 0; j < 8; ++j) split2(p[j >> 2][j & 3], ph8[j], pl8[j]);
    short8v pfh = *(short8v*)ph8;
    short8v pfl = *(short8v*)pl8;
    const u16* vbh = Vph + tb;
    const u16* vbl = Vpl + tb;
    __builtin_amdgcn_s_setprio(1);
#pragma unroll
    for (int dt = 0; dt < 8; ++dt) {
      int off = (loct * 128 + dt * 16 + lrow) * 8;
      short8v vh = *(const short8v*)&vbh[off];
      short8v vl = *(const short8v*)&vbl[off];
      o[dt] = mfma16(vh, pfh, o[dt]);
      o[dt] = mfma16(vh, pfl, o[dt]);
      o[dt] = mfma16(vl, pfh, o[dt]);
    }
    __builtin_amdgcn_s_setprio(0);
  }
  const size_t ob = (size_t)head * NCHUNK + ci;
  float* op = Opart + ob * 2048;
#pragma unroll
  for (int dt = 0; dt < 8; ++dt)
#pragma unroll
    for (int i = 0; i < 4; ++i) {
      int d = dt * 16 + loct * 4 + i;
      op[d * 16 + lrow] = o[dt][i];
    }
  if (loct == 0) {
    Mpart[ob * 16 + lrow] = mr;
    Lpart[ob * 16 + lrow] = lr;
  }
}

// ---------------- attention combine (round-10, passing) ----------------
__global__ __launch_bounds__(256) void attn_combine(const float* __restrict__ Opart,
                                                    const float* __restrict__ Mpart,
                                                    const float* __restrict__ Lpart,
                                                    const int* __restrict__ startOff,
                                                    u16* __restrict__ aoH,
                                                    u16* __restrict__ aoL) {
  const int qb = blockIdx.x, head = blockIdx.y;
  const int t = threadIdx.x;
  const int row = t >> 4, c8 = (t & 15) * 8;
  const int nkt = (qb >> 1) + 1;
  const int nch = (nkt + 7) >> 3;
  const int s0 = startOff[qb];
  const size_t hb = (size_t)head * NCHUNK;
  float M = -INFINITY;
  for (int ch = 0; ch < nch; ++ch)
    M = fmaxf(M, Mpart[(hb + s0 + ch) * 16 + row]);
  float L = 0.f;
  float acc[8];
#pragma unroll
  for (int j = 0; j < 8; ++j) acc[j] = 0.f;
  for (int ch = 0; ch < nch; ++ch) {
    const size_t cb = hb + s0 + ch;
    float sc = expf(Mpart[cb * 16 + row] - M);
    L += sc * Lpart[cb * 16 + row];
    const float* op = Opart + cb * 2048;
#pragma unroll
    for (int j = 0; j < 8; ++j)
      acc[j] += sc * op[(c8 + j) * 16 + row];
  }
  const float inv = 1.f / L;
  u16 h8[8], l8[8];
  float f[8];
#pragma unroll
  for (int j = 0; j < 8; ++j) f[j] = acc[j] * inv;
  split8(f, h8, l8);
  const size_t d = (size_t)(qb * 16 + row) * HID + head * HD + c8;
  *(uint4*)&aoH[d] = *(uint4*)h8;
  *(uint4*)&aoL[d] = *(uint4*)l8;
}

// ---------------- Gating (fp32; parallelized dot products) ----------------
__global__ __launch_bounds__(256) void gate_kernel(const float* __restrict__ x2,
                                                   const int* __restrict__ vmask,
                                                   const float* __restrict__ tg,
                                                   const float* __restrict__ vg,
                                                   const float* __restrict__ cbias,
                                                   int* __restrict__ counts,
                                                   int* __restrict__ ptok,
                                                   float* __restrict__ pw) {
  const int tok = blockIdx.x;
  const int t = threadIdx.x;
  __shared__ float xs[HID];
  __shared__ float part[4][NEXP];
  __shared__ float sc[NEXP];
  __shared__ float sb[NEXP];
  *(float4*)&xs[t * 4] = *(const float4*)(x2 + (size_t)tok * HID + t * 4);
  __syncthreads();
  const int vis = (vmask[tok] != 0) ? 1 : 0;
  const float* gw = vis ? vg : tg;
  {
    const int e = t & 63, pr = t >> 6;
    float acc = 0.f;
    for (int h = pr * 256; h < (pr + 1) * 256; ++h) acc += xs[h] * gw[h * NEXP + e];
    part[pr][e] = acc;
  }
  __syncthreads();
  if (t < NEXP) {
    float a = part[0][t] + part[1][t] + part[2][t] + part[3][t];
    float s = 1.f / (1.f + expf(-a));
    sc[t] = s;
    sb[t] = s + cbias[vis * NEXP + t];
  }
  __syncthreads();
  if (t == 0) {
    int chosen[NTOP];
    unsigned long long usedm = 0ULL;
    float wsum = 0.f;
    for (int k = 0; k < NTOP; ++k) {
      float best = -1e30f; int bi = 0;
      for (int e = 0; e < NEXP; ++e) {
        if ((usedm >> e) & 1ULL) continue;
        if (sb[e] > best) { best = sb[e]; bi = e; }
      }
      usedm |= (1ULL << bi);
      chosen[k] = bi;
      wsum += sc[bi];
    }
    const float inv = 1.f / wsum;
    for (int k = 0; k < NTOP; ++k) {
      int e = chosen[k];
      int slot = vis * NEXP + e;
      int pos = atomicAdd(&counts[slot], 1);
      ptok[slot * TT + pos] = tok;
      pw[slot * TT + pos] = sc[e] * inv;
    }
  }
}

__global__ void scan_kernel(const int* __restrict__ counts, int* __restrict__ rowoff) {
  if (threadIdx.x == 0 && blockIdx.x == 0) {
    int s = 0;
    for (int i = 0; i < 128; ++i) { rowoff[i] = s; s += counts[i]; }
    rowoff[128] = s;
  }
}

template<int MODE>
__device__ inline void act_base(const int* rowoff, int slot, size_t& eb, int& stride) {
  if (MODE == 0) { eb = (size_t)rowoff[slot] * 512; stride = 512; }
  else if (MODE == 1) {
    int Rt = rowoff[64];
    eb = (size_t)Rt * 512 + (size_t)(rowoff[slot] - Rt) * 256; stride = 256;
  } else { eb = SBASE; stride = 1024; }
}

// ---------------- streaming gate+up: 64-col tiles (round-13, passing; separate) -------
template<int IDIM, int MODE>
__global__ __launch_bounds__(256) void gateup_stream(const u16* __restrict__ X,
                                                     const float* __restrict__ WG,
                                                     const float* __restrict__ WU,
                                                     const int* __restrict__ counts,
                                                     const int* __restrict__ ptok,
                                                     const float* __restrict__ pw,
                                                     const int* __restrict__ rowoff,
                                                     u16* __restrict__ ACT) {
  __shared__ u16 sG[2][8192], sU[2][8192];   // 128 k x 64 cols, double-buffered
  __shared__ int toksL[256];
  __shared__ float twsL[256];
  const int c0 = blockIdx.x * 64;
  int cnt, mstart, mend, slot = 0;
  size_t eb; int stride;
  const float *wgp, *wup;
  if (MODE == 2) {
    cnt = TT; mstart = blockIdx.y * 256; mend = mstart + 256;
    eb = SBASE; stride = 1024;
    wgp = WG; wup = WU;
  } else {
    const int e = blockIdx.y;
    slot = (MODE == 1 ? NEXP : 0) + e;
    cnt = counts[slot];
    mstart = 0; mend = cnt;
    act_base<MODE>(rowoff, slot, eb, stride);
    wgp = WG + (size_t)e * HID * IDIM;
    wup = WU + (size_t)e * HID * IDIM;
  }
  if (mstart >= mend) return;
  const int w = threadIdx.x >> 6, lane = threadIdx.x & 63;
  const int lrow = lane & 15, loct = lane >> 4;

  for (int m0 = mstart; m0 < mend; m0 += 256) {
    {
      int gi = m0 + threadIdx.x;
      int tok = 0; float tw = 0.f;
      if (gi < cnt) {
        tok = (MODE == 2) ? gi : ptok[slot * TT + gi];
        tw  = (MODE == 2) ? 1.f : pw[slot * TT + gi];
      }
      toksL[threadIdx.x] = tok; twsL[threadIdx.x] = tw;
    }
    float4 rg[8], ru[8];
    wload64(wgp, IDIM, c0, 0, rg);
    wload64(wup, IDIM, c0, 0, ru);
    __syncthreads();
    wwrite64(rg, sG[0]);
    wwrite64(ru, sU[0]);
    const u16* xr[4];
#pragma unroll
    for (int tt = 0; tt < 4; ++tt)
      xr[tt] = X + (size_t)toksL[(w + tt * 4) * 16 + lrow] * HID;
    f32x4 aG[4][4], aU[4][4];
#pragma unroll
    for (int tt = 0; tt < 4; ++tt)
#pragma unroll
      for (int cf = 0; cf < 4; ++cf) {
        aG[tt][cf] = (f32x4){0.f,0.f,0.f,0.f};
        aU[tt][cf] = (f32x4){0.f,0.f,0.f,0.f};
      }
    __syncthreads();
    for (int c = 0; c < HID / 128; ++c) {
      const int cur = c & 1;
      if (c + 1 < HID / 128) {
        wload64(wgp, IDIM, c0, (c + 1) * 128, rg);
        wload64(wup, IDIM, c0, (c + 1) * 128, ru);
      }
#pragma unroll
      for (int ks = 0; ks < 4; ++ks) {
        short8v a[4];
#pragma unroll
        for (int tt = 0; tt < 4; ++tt)
          a[tt] = *(const short8v*)&xr[tt][c * 128 + ks * 32 + loct * 8];
        const int gbase = ((ks * 4 + loct) * 64 + lrow) * 8;
#pragma unroll
        for (int cf = 0; cf < 4; ++cf) {
          short8v bg = *(const short8v*)&sG[cur][gbase + cf * 128];
          short8v bu = *(const short8v*)&sU[cur][gbase + cf * 128];
#pragma unroll
          for (int tt = 0; tt < 4; ++tt) {
            aG[tt][cf] = mfma16(a[tt], bg, aG[tt][cf]);
            aU[tt][cf] = mfma16(a[tt], bu, aU[tt][cf]);
          }
        }
      }
      if (c + 1 < HID / 128) {
        wwrite64(rg, sG[cur ^ 1]);
        wwrite64(ru, sU[cur ^ 1]);
      }
      __syncthreads();
    }
#pragma unroll
    for (int tt = 0; tt < 4; ++tt) {
      const int ti = w + tt * 4;
#pragma unroll
      for (int i = 0; i < 4; ++i) {
        const int r = loct * 4 + i;
        const int gi = m0 + ti * 16 + r;
        if (gi < cnt) {
          const float twv = twsL[ti * 16 + r];
#pragma unroll
          for (int cf = 0; cf < 4; ++cf) {
            float g = aG[tt][cf][i], u = aU[tt][cf][i];
            float a = g / (1.f + expf(-g)) * u * twv;
            ACT[eb + (size_t)gi * stride + c0 + cf * 16 + lrow] = f2bf(a);
          }
        }
      }
    }
    __syncthreads();
  }
}

// ---------------- down body: 128-col tiles, 64-k chunks (A-traffic halved) ------------
template<int KDIM, int MODE>
__device__ __forceinline__ void down_body(int cch, int eg,
    const u16* __restrict__ ACT, const float* __restrict__ WD,
    const int* __restrict__ counts, const int* __restrict__ ptok,
    const int* __restrict__ rowoff, float* __restrict__ OUT,
    u16 (&sW)[2][8192], int (&toksL)[256]) {
  const int c0 = cch * 128;
  int cnt, mstart, mend, slot = 0;
  size_t eb; int stride;
  const float* wdp;
  if (MODE == 2) {
    cnt = TT; mstart = eg * 256; mend = mstart + 256;
    eb = SBASE; stride = 1024;
    wdp = WD;
  } else {
    slot = (MODE == 1 ? NEXP : 0) + eg;
    cnt = counts[slot];
    mstart = 0; mend = cnt;
    act_base<MODE>(rowoff, slot, eb, stride);
    wdp = WD + (size_t)eg * KDIM * HID;
  }
  if (mstart >= mend) return;
  const int w = threadIdx.x >> 6, lane = threadIdx.x & 63;
  const int lrow = lane & 15, loct = lane >> 4;
  constexpr int NC = KDIM / 64;

  for (int m0 = mstart; m0 < mend; m0 += 256) {
    {
      int gi = m0 + threadIdx.x;
      int tok = 0;
      if (gi < cnt) tok = (MODE == 2) ? gi : ptok[slot * TT + gi];
      toksL[threadIdx.x] = tok;
    }
    float4 rw[8];
    wload128(wdp, HID, c0, 0, rw);
    __syncthreads();
    wwrite128(rw, sW[0]);
    const u16* ar[4];
#pragma unroll
    for (int tt = 0; tt < 4; ++tt) {
      int gi = m0 + (w + tt * 4) * 16 + lrow;
      int gc = (gi < cnt) ? gi : (cnt - 1);
      ar[tt] = ACT + eb + (size_t)gc * stride;
    }
    f32x4 acc[4][8];
#pragma unroll
    for (int tt = 0; tt < 4; ++tt)
#pragma unroll
      for (int cf = 0; cf < 8; ++cf) acc[tt][cf] = (f32x4){0.f,0.f,0.f,0.f};
    __syncthreads();
    for (int c = 0; c < NC; ++c) {
      const int cur = c & 1;
      if (c + 1 < NC) wload128(wdp, HID, c0, (c + 1) * 64, rw);
#pragma unroll
      for (int ks = 0; ks < 2; ++ks) {
        short8v a[4];
#pragma unroll
        for (int tt = 0; tt < 4; ++tt)
          a[tt] = *(const short8v*)&ar[tt][c * 64 + ks * 32 + loct * 8];
        const int gbase = ((ks * 4 + loct) * 128 + lrow) * 8;
#pragma unroll
        for (int cf = 0; cf < 8; ++cf) {
          short8v b = *(const short8v*)&sW[cur][gbase + cf * 128];
#pragma unroll
          for (int tt = 0; tt < 4; ++tt)
            acc[tt][cf] = mfma16(a[tt], b, acc[tt][cf]);
        }
      }
      if (c + 1 < NC) wwrite128(rw, sW[cur ^ 1]);
      __syncthreads();
    }
#pragma unroll
    for (int tt = 0; tt < 4; ++tt) {
      const int ti = w + tt * 4;
#pragma unroll
      for (int i = 0; i < 4; ++i) {
        const int r = loct * 4 + i;
        const int gi = m0 + ti * 16 + r;
        if (gi < cnt) {
          const int tok = toksL[ti * 16 + r];
#pragma unroll
          for (int cf = 0; cf < 8; ++cf)
            atomicAdd(&OUT[(size_t)tok * HID + c0 + cf * 16 + lrow], acc[tt][cf][i]);
        }
      }
    }
    __syncthreads();
  }
}

// fused: text 512 (8cch x 64e) | vision 512 | shared 64 (8 x 8); 1088 = 8*136
__global__ __launch_bounds__(256) void down_fused(const u16* __restrict__ ACT,
    const float* __restrict__ swd, const float* __restrict__ twd,
    const float* __restrict__ vwd,
    const int* __restrict__ counts, const int* __restrict__ ptok,
    const int* __restrict__ rowoff, float* __restrict__ OUT) {
  __shared__ u16 sW[2][8192];
  __shared__ int toksL[256];
  const int P = blockIdx.x;
  const int L = (P & 7) * 136 + (P >> 3);   // bijective, expert-contiguous per XCD
  if (L < 512)
    down_body<I_T, 0>(L & 7, L >> 3, ACT, twd, counts, ptok, rowoff, OUT, sW, toksL);
  else if (L < 1024) {
    int l = L - 512;
    down_body<I_V, 1>(l & 7, l >> 3, ACT, vwd, counts, ptok, rowoff, OUT, sW, toksL);
  } else {
    int l = L - 1024;
    down_body<I_S, 2>(l & 7, l >> 3, ACT, swd, counts, ptok, rowoff, OUT, sW, toksL);
  }
}

// ---------------- out = a + b ----------------
__global__ __launch_bounds__(256) void add2_kernel(const float* __restrict__ a,
                                                   const float* __restrict__ b,
                                                   float* __restrict__ out) {
  const size_t i = ((size_t)blockIdx.x * 256 + threadIdx.x) * 4;
  const float4 va = *(const float4*)(a + i);
  const float4 vb = *(const float4*)(b + i);
  float4 o;
  o.x = va.x + vb.x; o.y = va.y + vb.y; o.z = va.z + vb.z; o.w = va.w + vb.w;
  *(float4*)(out + i) = o;
}

extern "C" void kernel_launch(void* const* d_in, const int* in_sizes, int n_in,
                              void* d_out, int out_size, void* d_ws, size_t ws_size,
                              hipStream_t stream) {
  const float* hidden   = (const float*)d_in[0];
  const int*   positions= (const int*)d_in[1];
  const int*   vmask    = (const int*)d_in[2];
  const float* w_qkv    = (const float*)d_in[3];
  const float* w_o      = (const float*)d_in[4];
  const float* ln1      = (const float*)d_in[5];
  const float* ln2      = (const float*)d_in[6];
  const float* tgw      = (const float*)d_in[7];
  const float* vgw      = (const float*)d_in[8];
  const float* cbias    = (const float*)d_in[9];
  const float* twg      = (const float*)d_in[10];
  const float* twu      = (const float*)d_in[11];
  const float* twd      = (const float*)d_in[12];
  const float* vwg      = (const float*)d_in[13];
  const float* vwu      = (const float*)d_in[14];
  const float* vwd      = (const float*)d_in[15];
  const float* swg      = (const float*)d_in[16];
  const float* swu      = (const float*)d_in[17];
  const float* swd      = (const float*)d_in[18];
  float* out = (float*)d_out;

  char* ws = (char*)d_ws;
  size_t off = 0;
  auto alloc = [&](size_t bytes) -> void* {
    void* p = ws + off;
    off += (bytes + 255) & ~(size_t)255;
    return p;
  };
  u16*   xbh   = (u16*)alloc((size_t)TT * HID * 2);
  u16*   xbl   = (u16*)alloc((size_t)TT * HID * 2);
  float* qkv   = (float*)alloc((size_t)TT * QKVN * 4);
  u16*   aoH   = (u16*)alloc((size_t)TT * HID * 2);
  u16*   aoL   = (u16*)alloc((size_t)TT * HID * 2);
  float* hbuf  = (float*)alloc((size_t)TT * HID * 4);
  float* x2    = (float*)alloc((size_t)TT * HID * 4);
  u16*   xb2   = (u16*)alloc((size_t)TT * HID * 2);
  float* moe   = (float*)alloc((size_t)TT * HID * 4);
  u16*   ACT   = (u16*)alloc((SBASE + (size_t)TT * 1024) * 2);
  u16*   Qph   = (u16*)alloc((size_t)TT * HID * 2);
  u16*   Qpl   = (u16*)alloc((size_t)TT * HID * 2);
  u16*   Kph   = (u16*)alloc((size_t)NKVH * TT * HD * 2);
  u16*   Kpl   = (u16*)alloc((size_t)NKVH * TT * HD * 2);
  u16*   Vph   = (u16*)alloc((size_t)NKVH * TT * HD * 2);
  u16*   Vpl   = (u16*)alloc((size_t)NKVH * TT * HD * 2);
  float* Opart = (float*)alloc((size_t)NHEAD * NCHUNK * 16 * 128 * 4);
  float* Mpart = (float*)alloc((size_t)NHEAD * NCHUNK * 16 * 4);
  float* Lpart = (float*)alloc((size_t)NHEAD * NCHUNK * 16 * 4);
  int*   ctab  = (int*)alloc(NCHUNK * 4);
  int*   cstart= (int*)alloc((TT / 16) * 4);
  int*   counts= (int*)alloc(128 * 4);
  int*   rowoff= (int*)alloc(129 * 4);
  int*   ptok  = (int*)alloc((size_t)128 * TT * 4);
  float* pwgt  = (float*)alloc((size_t)128 * TT * 4);

  hipMemsetAsync(counts, 0, 128 * 4, stream);
  hipMemsetAsync(moe, 0, (size_t)TT * HID * 4, stream);

  // one-time tables (parallel, closed-form)
  chunk_setup<<<1, 128, 0, stream>>>(ctab, cstart);

  // pre-gate path, split-bf16 precision (weights streamed fp32 in-kernel)
  rmsnorm_kernel<false, true, true><<<TT, 256, 0, stream>>>(hidden, ln1, nullptr, xbh, xbl);
  dense_stream<false><<<dim3(QKVN / 64, TT / 128), 256, 0, stream>>>(xbh, xbl, w_qkv, nullptr, qkv, QKVN);
  pack_qkv<<<TT / 32, 256, 0, stream>>>(qkv, positions, Qph, Qpl, Kph, Kpl, Vph, Vpl);
  attn_part<<<dim3(NCHUNK, NKVH), 256, 0, stream>>>(Qph, Qpl, Kph, Kpl, Vph, Vpl, ctab, Opart, Mpart, Lpart);
  attn_combine<<<dim3(TT / 16, NHEAD), 256, 0, stream>>>(Opart, Mpart, Lpart, cstart, aoH, aoL);
  dense_stream<true><<<dim3(HID / 64, TT / 128), 256, 0, stream>>>(aoH, aoL, w_o, hidden, hbuf, HID);
  rmsnorm_kernel<true, true, false><<<TT, 256, 0, stream>>>(hbuf, ln2, x2, xb2, nullptr);
  gate_kernel<<<TT, 256, 0, stream>>>(x2, vmask, tgw, vgw, cbias, counts, ptok, pwgt);
  scan_kernel<<<1, 64, 0, stream>>>(counts, rowoff);

  // MoE + shared MLP: separate 64-col gateup dispatches + 128-col fused down
  gateup_stream<I_S, 2><<<dim3(I_S / 64, 8), 256, 0, stream>>>(xb2, swg, swu, nullptr, nullptr, nullptr, rowoff, ACT);
  gateup_stream<I_T, 0><<<dim3(I_T / 64, NEXP), 256, 0, stream>>>(xb2, twg, twu, counts, ptok, pwgt, rowoff, ACT);
  gateup_stream<I_V, 1><<<dim3(I_V / 64, NEXP), 256, 0, stream>>>(xb2, vwg, vwu, counts, ptok, pwgt, rowoff, ACT);

  down_fused<<<1088, 256, 0, stream>>>(ACT, swd, twd, vwd, counts, ptok, rowoff, moe);

  add2_kernel<<<(TT * HID) / 1024, 256, 0, stream>>>(hbuf, moe, out);
}

// Round 17
// 677.259 us; speedup vs baseline: 1.0760x; 1.0760x over previous
//
#include <hip/hip_runtime.h>
#include <hip/hip_bf16.h>
#include <math.h>

#define TT   2048
#define HID  1024
#define NHEAD 8
#define NKVH  2
#define HD   128
#define QKVN 1536
#define NEXP 64
#define NTOP 6
#define I_T  512
#define I_V  256
#define I_S  1024
#define SBASE ((size_t)12288 * 512)   // ACT elem offset of shared region
#define NCHUNK 576                    // sum over qb of ceil(((qb>>1)+1)/8)

typedef unsigned short u16;
typedef __attribute__((ext_vector_type(8))) short short8v;
typedef __attribute__((ext_vector_type(4))) float f32x4;

__device__ inline u16 f2bf(float f) {
  __hip_bfloat16 h = __float2bfloat16(f);
  return *reinterpret_cast<u16*>(&h);
}
__device__ inline float bfu2f(u16 u) {
  unsigned x = ((unsigned)u) << 16;
  return __uint_as_float(x);
}
__device__ inline void split2(float f, u16& h, u16& l) {
  h = f2bf(f);
  l = f2bf(f - bfu2f(h));
}
__device__ inline void split8(const float* f, u16* h, u16* l) {
#pragma unroll
  for (int i = 0; i < 8; ++i) split2(f[i], h[i], l[i]);
}

__device__ inline f32x4 mfma16(short8v a, short8v b, f32x4 c) {
  return __builtin_amdgcn_mfma_f32_16x16x32_bf16(a, b, c, 0, 0, 0);
}

// ---- 64-col weight-chunk staging: 128 k-rows x 64 cols, fp32 -> bf16 LDS
// LDS layout (k-packed-8): elem(k,c) at ((k>>3)*64 + c)*8 + (k&7)
__device__ inline void wload64(const float* __restrict__ W, int ldw, int c0, int kc,
                               float4* r) {
  const int t = threadIdx.x;
  const int c4 = (t & 15) << 2;
  const int r0 = t >> 4;
#pragma unroll
  for (int j = 0; j < 8; ++j)
    r[j] = *(const float4*)&W[(size_t)(kc + r0 + j * 16) * ldw + c0 + c4];
}
__device__ inline void wwrite64(const float4* r, u16* lds) {
  const int t = threadIdx.x;
  const int c4 = (t & 15) << 2;
  const int r0 = t >> 4;
#pragma unroll
  for (int j = 0; j < 8; ++j) {
    int k = r0 + j * 16;
    u16* dst = lds + ((size_t)(k >> 3) * 64 + c4) * 8 + (k & 7);
    float4 v = r[j];
    dst[0]  = f2bf(v.x);
    dst[8]  = f2bf(v.y);
    dst[16] = f2bf(v.z);
    dst[24] = f2bf(v.w);
  }
}
// hi/lo variant for the dense (split-precision) path
__device__ inline void wwrite64hl(const float4* r, u16* ldsH, u16* ldsL) {
  const int t = threadIdx.x;
  const int c4 = (t & 15) << 2;
  const int r0 = t >> 4;
#pragma unroll
  for (int j = 0; j < 8; ++j) {
    int k = r0 + j * 16;
    size_t base = ((size_t)(k >> 3) * 64 + c4) * 8 + (k & 7);
    float4 v = r[j];
    u16 h, l;
    split2(v.x, h, l); ldsH[base]      = h; ldsL[base]      = l;
    split2(v.y, h, l); ldsH[base + 8]  = h; ldsL[base + 8]  = l;
    split2(v.z, h, l); ldsH[base + 16] = h; ldsL[base + 16] = l;
    split2(v.w, h, l); ldsH[base + 24] = h; ldsL[base + 24] = l;
  }
}

// ---------------- RMSNorm (templated outputs: fp32, bf16-hi, bf16-lo) ----------------
template<bool F32, bool BF, bool LO>
__global__ __launch_bounds__(256) void rmsnorm_kernel(const float* __restrict__ x,
                                                      const float* __restrict__ w,
                                                      float* __restrict__ o32,
                                                      u16* __restrict__ obfH,
                                                      u16* __restrict__ obfL) {
  const int row = blockIdx.x;
  const int t = threadIdx.x;
  const float4 v = *(const float4*)(x + (size_t)row * HID + t * 4);
  float ss = v.x*v.x + v.y*v.y + v.z*v.z + v.w*v.w;
#pragma unroll
  for (int m = 32; m >= 1; m >>= 1) ss += __shfl_xor(ss, m);
  __shared__ float red[4];
  __shared__ float rrs;
  if ((t & 63) == 0) red[t >> 6] = ss;
  __syncthreads();
  if (t == 0) rrs = rsqrtf((red[0] + red[1] + red[2] + red[3]) * (1.0f / HID) + 1e-5f);
  __syncthreads();
  const float rr = rrs;
  const float4 wv = *(const float4*)(w + t * 4);
  float o[4];
  o[0] = v.x * wv.x * rr; o[1] = v.y * wv.y * rr;
  o[2] = v.z * wv.z * rr; o[3] = v.w * wv.w * rr;
  if (F32) *(float4*)(o32 + (size_t)row * HID + t * 4) = *(float4*)o;
  if (BF) {
    u16 h[4], l[4];
#pragma unroll
    for (int i = 0; i < 4; ++i) split2(o[i], h[i], l[i]);
    *(uint2*)(obfH + (size_t)row * HID + t * 4) = *(uint2*)h;
    if (LO) *(uint2*)(obfL + (size_t)row * HID + t * 4) = *(uint2*)l;
  }
}

// ---------------- dense streaming split-bf16 GEMM (round-13, passing) ----------------
template<bool RES>
__global__ __launch_bounds__(256) void dense_stream(const u16* __restrict__ AH,
                                                    const u16* __restrict__ AL,
                                                    const float* __restrict__ W,
                                                    const float* __restrict__ resid,
                                                    float* __restrict__ C, int N) {
  __shared__ u16 sWH[8192], sWL[8192];
  const int c0 = blockIdx.x * 64;
  const int m0 = blockIdx.y * 128;
  const int w = threadIdx.x >> 6, lane = threadIdx.x & 63;
  const int lrow = lane & 15, loct = lane >> 4;
  const int rbase = m0 + w * 32;

  f32x4 acc[2][4];
#pragma unroll
  for (int rt = 0; rt < 2; ++rt)
#pragma unroll
    for (int cf = 0; cf < 4; ++cf) acc[rt][cf] = (f32x4){0.f,0.f,0.f,0.f};

  float4 rw[8];
  wload64(W, N, c0, 0, rw);
  wwrite64hl(rw, sWH, sWL);
  __syncthreads();
  for (int c = 0; c < 8; ++c) {
    if (c + 1 < 8) wload64(W, N, c0, (c + 1) * 128, rw);
#pragma unroll
    for (int ks = 0; ks < 4; ++ks) {
      short8v ah[2], al[2];
#pragma unroll
      for (int rt = 0; rt < 2; ++rt) {
        size_t g = (size_t)(rbase + rt * 16 + lrow) * HID + c * 128 + ks * 32 + loct * 8;
        ah[rt] = *(const short8v*)&AH[g];
        al[rt] = *(const short8v*)&AL[g];
      }
      const int gbase = ((ks * 4 + loct) * 64 + lrow) * 8;
#pragma unroll
      for (int cf = 0; cf < 4; ++cf) {
        short8v bh = *(const short8v*)&sWH[gbase + cf * 128];
        short8v bl = *(const short8v*)&sWL[gbase + cf * 128];
#pragma unroll
        for (int rt = 0; rt < 2; ++rt) {
          acc[rt][cf] = mfma16(ah[rt], bh, acc[rt][cf]);
          acc[rt][cf] = mfma16(ah[rt], bl, acc[rt][cf]);
          acc[rt][cf] = mfma16(al[rt], bh, acc[rt][cf]);
          acc[rt][cf] = mfma16(al[rt], bl, acc[rt][cf]);
        }
      }
    }
    __syncthreads();
    if (c + 1 < 8) {
      wwrite64hl(rw, sWH, sWL);
      __syncthreads();
    }
  }
#pragma unroll
  for (int rt = 0; rt < 2; ++rt)
#pragma unroll
    for (int cf = 0; cf < 4; ++cf)
#pragma unroll
      for (int i = 0; i < 4; ++i) {
        int row = rbase + rt * 16 + loct * 4 + i;
        int col = c0 + cf * 16 + lrow;
        float v = acc[rt][cf][i];
        if (RES) v += resid[(size_t)row * N + col];
        C[(size_t)row * N + col] = v;
      }
}

// ---------------- pack_qkv: rope + hi/lo split into MFMA-layout buffers ----------------
// V stored KEY-PERMUTED for swapped-PV A-operand: slot (g,j) holds key (j>>2)*16+g*4+(j&3)
__global__ __launch_bounds__(256) void pack_qkv(const float* __restrict__ qkv,
                                                const int* __restrict__ pos,
                                                u16* __restrict__ Qh, u16* __restrict__ Ql,
                                                u16* __restrict__ Kph, u16* __restrict__ Kpl,
                                                u16* __restrict__ Vph, u16* __restrict__ Vpl) {
  const int tile = blockIdx.x;
  const int t = threadIdx.x;
  __shared__ float cs[2048], sn[2048];   // [tok32][fi]
  for (int i = t; i < 2048; i += 256) {
    int tok32 = i >> 6, fi = i & 63;
    int tok = tile * 32 + tok32;
    int axis = (fi < 22) ? 0 : (fi < 44 ? 1 : 2);
    float posv = (float)pos[axis * TT + tok];
    float invf = powf(500000.0f, -((float)(2 * fi)) / 128.0f);
    float ang = posv * invf;
    sincosf(ang, &sn[i], &cs[i]);
  }
  __syncthreads();
  for (int task = t; task < 4096; task += 256) {
    int h = task >> 9;
    int rem = task & 511;
    int tok32 = rem >> 4, fi4 = rem & 15;
    int tok = tile * 32 + tok32;
    const float* src = qkv + (size_t)tok * QKVN + h * HD + fi4 * 8;
    float4 v0 = *(const float4*)src, v1 = *(const float4*)(src + 4);
    float f[8] = {v0.x, v0.y, v0.z, v0.w, v1.x, v1.y, v1.z, v1.w};
    float o[8];
#pragma unroll
    for (int j = 0; j < 4; ++j) {
      int fi = fi4 * 4 + j;
      float c = cs[tok32 * 64 + fi], s = sn[tok32 * 64 + fi];
      o[2*j]   = f[2*j] * c - f[2*j+1] * s;
      o[2*j+1] = f[2*j] * s + f[2*j+1] * c;
    }
    u16 h8[8], l8[8];
    split8(o, h8, l8);
    size_t d = (size_t)tok * HID + h * HD + fi4 * 8;
    *(uint4*)&Qh[d] = *(uint4*)h8;
    *(uint4*)&Ql[d] = *(uint4*)l8;
  }
  for (int task = t; task < 1024; task += 256) {
    int kvh = task >> 9;
    int rem = task & 511;
    int kk = rem >> 4, fi4 = rem & 15;
    int tok = tile * 32 + kk;
    const float* src = qkv + (size_t)tok * QKVN + NHEAD * HD + kvh * HD + fi4 * 8;
    float4 v0 = *(const float4*)src, v1 = *(const float4*)(src + 4);
    float f[8] = {v0.x, v0.y, v0.z, v0.w, v1.x, v1.y, v1.z, v1.w};
    float o[8];
#pragma unroll
    for (int j = 0; j < 4; ++j) {
      int fi = fi4 * 4 + j;
      float c = cs[kk * 64 + fi], s = sn[kk * 64 + fi];
      o[2*j]   = f[2*j] * c - f[2*j+1] * s;
      o[2*j+1] = f[2*j] * s + f[2*j+1] * c;
    }
    u16 h8[8], l8[8];
    split8(o, h8, l8);
    size_t d = ((size_t)(kvh * 64 + tile) << 12) + (size_t)(fi4 * 32 + kk) * 8;
    *(uint4*)&Kph[d] = *(uint4*)h8;
    *(uint4*)&Kpl[d] = *(uint4*)l8;
  }
  for (int task = t; task < 1024; task += 256) {
    int kvh = task >> 9;
    int rem = task & 511;
    int g = rem >> 7, dcol = rem & 127;
    float f[8];
#pragma unroll
    for (int e = 0; e < 8; ++e) {
      int key = ((e >> 2) * 16) + g * 4 + (e & 3);   // permuted for P-frag match
      f[e] = qkv[(size_t)(tile * 32 + key) * QKVN + (NHEAD + NKVH) * HD + kvh * HD + dcol];
    }
    u16 h8[8], l8[8];
    split8(f, h8, l8);
    size_t d = ((size_t)(kvh * 64 + tile) << 12) + (size_t)(g * 128 + dcol) * 8;
    *(uint4*)&Vph[d] = *(uint4*)h8;
    *(uint4*)&Vpl[d] = *(uint4*)l8;
  }
}

// ---------------- chunk table setup (parallel, closed-form startOff) ----------------
__global__ void chunk_setup(int* __restrict__ tab, int* __restrict__ startOff) {
  const int qb = threadIdx.x;
  if (qb < TT / 16) {
    const int g = qb >> 4, r = qb & 15;
    const int s0 = qb + 16 * (g * (g - 1) / 2) + r * g;  // sum_{q<qb} ((q>>4)+1)
    startOff[qb] = s0;
    const int nch = g + 1;                                // ceil(((qb>>1)+1)/8)
    for (int c = 0; c < nch; ++c) tab[s0 + c] = qb * 16 + c;
  }
}

// ---------------- attention partial, SWAPPED QK^T (round-10, passing) ----------------
__global__ __launch_bounds__(256) void attn_part(const u16* __restrict__ Qh,
                                                 const u16* __restrict__ Ql,
                                                 const u16* __restrict__ Kph,
                                                 const u16* __restrict__ Kpl,
                                                 const u16* __restrict__ Vph,
                                                 const u16* __restrict__ Vpl,
                                                 const int* __restrict__ tab,
                                                 float* __restrict__ Opart,
                                                 float* __restrict__ Mpart,
                                                 float* __restrict__ Lpart) {
  const int ci = blockIdx.x;
  const int kvh = blockIdx.y;
  const int w = threadIdx.x >> 6, lane = threadIdx.x & 63;
  const int head = kvh * 4 + w;
  const int ent = tab[ci];
  const int qb = ent >> 4, cc = ent & 15;
  const int qw0 = qb * 16;
  const int lrow = lane & 15, loct = lane >> 4;
  const int nkt = (qb >> 1) + 1;
  const int kt0 = cc * 8, kt1 = min(kt0 + 8, nkt);

  short8v qh[4], ql[4];
  {
    const size_t qoff = (size_t)(qw0 + lrow) * HID + head * HD + loct * 8;
#pragma unroll
    for (int dc = 0; dc < 4; ++dc) {
      qh[dc] = *(const short8v*)&Qh[qoff + dc * 32];
      ql[dc] = *(const short8v*)&Ql[qoff + dc * 32];
    }
  }

  f32x4 o[8];
#pragma unroll
  for (int dt = 0; dt < 8; ++dt) o[dt] = (f32x4){0.f,0.f,0.f,0.f};
  float mr = -INFINITY, lr = 0.f;
  const float scale = 0.08838834764831845f;

  for (int kt = kt0; kt < kt1; ++kt) {
    const int kv0 = kt * 32;
    const size_t tb = ((size_t)(kvh * 64 + kt) << 12);
    const u16* kbh = Kph + tb;
    const u16* kbl = Kpl + tb;
    f32x4 s[2];
    __builtin_amdgcn_s_setprio(1);
#pragma unroll
    for (int nt = 0; nt < 2; ++nt) {
      f32x4 shh = {0.f,0.f,0.f,0.f}, shl = {0.f,0.f,0.f,0.f};
      f32x4 slh = {0.f,0.f,0.f,0.f};
#pragma unroll
      for (int dc = 0; dc < 4; ++dc) {
        int off = ((dc * 4 + loct) * 32 + nt * 16 + lrow) * 8;
        short8v kh = *(const short8v*)&kbh[off];
        short8v kl = *(const short8v*)&kbl[off];
        shh = mfma16(kh, qh[dc], shh);
        shl = mfma16(kh, ql[dc], shl);
        slh = mfma16(kl, qh[dc], slh);
      }
      s[nt] = shh + (shl + slh);
    }
    __builtin_amdgcn_s_setprio(0);
    const int qrow = qw0 + lrow;
    float rmax = -INFINITY;
#pragma unroll
    for (int nt = 0; nt < 2; ++nt)
#pragma unroll
      for (int i = 0; i < 4; ++i) {
        int key = kv0 + nt * 16 + loct * 4 + i;
        float v = s[nt][i] * scale;
        s[nt][i] = (key <= qrow) ? v : -INFINITY;
        rmax = fmaxf(rmax, s[nt][i]);
      }
    rmax = fmaxf(rmax, __shfl_xor(rmax, 16));
    rmax = fmaxf(rmax, __shfl_xor(rmax, 32));
    const float mn = fmaxf(mr, rmax);
    const float corr = expf(mr - mn);
    mr = mn;
    float p[2][4];
    float ps = 0.f;
#pragma unroll
    for (int nt = 0; nt < 2; ++nt)
#pragma unroll
      for (int i = 0; i < 4; ++i) { p[nt][i] = expf(s[nt][i] - mr); ps += p[nt][i]; }
    ps += __shfl_xor(ps, 16);
    ps += __shfl_xor(ps, 32);
    lr = lr * corr + ps;
#pragma unroll
    for (int dt = 0; dt < 8; ++dt)
#pragma unroll
      for (int i = 0; i < 4; ++i) o[dt][i] *= corr;
    u16 ph8[8], pl8[8];
#pragma unroll
    for (int j = 0; j < 8; ++j) split2(p[j >> 2][j & 3], ph8[j], pl8[j]);
    short8v pfh = *(short8v*)ph8;
    short8v pfl = *(short8v*)pl8;
    const u16* vbh = Vph + tb;
    const u16* vbl = Vpl + tb;
    __builtin_amdgcn_s_setprio(1);
#pragma unroll
    for (int dt = 0; dt < 8; ++dt) {
      int off = (loct * 128 + dt * 16 + lrow) * 8;
      short8v vh = *(const short8v*)&vbh[off];
      short8v vl = *(const short8v*)&vbl[off];
      o[dt] = mfma16(vh, pfh, o[dt]);
      o[dt] = mfma16(vh, pfl, o[dt]);
      o[dt] = mfma16(vl, pfh, o[dt]);
    }
    __builtin_amdgcn_s_setprio(0);
  }
  const size_t ob = (size_t)head * NCHUNK + ci;
  float* op = Opart + ob * 2048;
#pragma unroll
  for (int dt = 0; dt < 8; ++dt)
#pragma unroll
    for (int i = 0; i < 4; ++i) {
      int d = dt * 16 + loct * 4 + i;
      op[d * 16 + lrow] = o[dt][i];
    }
  if (loct == 0) {
    Mpart[ob * 16 + lrow] = mr;
    Lpart[ob * 16 + lrow] = lr;
  }
}

// ---------------- attention combine (round-10, passing) ----------------
__global__ __launch_bounds__(256) void attn_combine(const float* __restrict__ Opart,
                                                    const float* __restrict__ Mpart,
                                                    const float* __restrict__ Lpart,
                                                    const int* __restrict__ startOff,
                                                    u16* __restrict__ aoH,
                                                    u16* __restrict__ aoL) {
  const int qb = blockIdx.x, head = blockIdx.y;
  const int t = threadIdx.x;
  const int row = t >> 4, c8 = (t & 15) * 8;
  const int nkt = (qb >> 1) + 1;
  const int nch = (nkt + 7) >> 3;
  const int s0 = startOff[qb];
  const size_t hb = (size_t)head * NCHUNK;
  float M = -INFINITY;
  for (int ch = 0; ch < nch; ++ch)
    M = fmaxf(M, Mpart[(hb + s0 + ch) * 16 + row]);
  float L = 0.f;
  float acc[8];
#pragma unroll
  for (int j = 0; j < 8; ++j) acc[j] = 0.f;
  for (int ch = 0; ch < nch; ++ch) {
    const size_t cb = hb + s0 + ch;
    float sc = expf(Mpart[cb * 16 + row] - M);
    L += sc * Lpart[cb * 16 + row];
    const float* op = Opart + cb * 2048;
#pragma unroll
    for (int j = 0; j < 8; ++j)
      acc[j] += sc * op[(c8 + j) * 16 + row];
  }
  const float inv = 1.f / L;
  u16 h8[8], l8[8];
  float f[8];
#pragma unroll
  for (int j = 0; j < 8; ++j) f[j] = acc[j] * inv;
  split8(f, h8, l8);
  const size_t d = (size_t)(qb * 16 + row) * HID + head * HD + c8;
  *(uint4*)&aoH[d] = *(uint4*)h8;
  *(uint4*)&aoL[d] = *(uint4*)l8;
}

// ---------------- Gating (fp32; parallelized dot products) ----------------
__global__ __launch_bounds__(256) void gate_kernel(const float* __restrict__ x2,
                                                   const int* __restrict__ vmask,
                                                   const float* __restrict__ tg,
                                                   const float* __restrict__ vg,
                                                   const float* __restrict__ cbias,
                                                   int* __restrict__ counts,
                                                   int* __restrict__ ptok,
                                                   float* __restrict__ pw) {
  const int tok = blockIdx.x;
  const int t = threadIdx.x;
  __shared__ float xs[HID];
  __shared__ float part[4][NEXP];
  __shared__ float sc[NEXP];
  __shared__ float sb[NEXP];
  *(float4*)&xs[t * 4] = *(const float4*)(x2 + (size_t)tok * HID + t * 4);
  __syncthreads();
  const int vis = (vmask[tok] != 0) ? 1 : 0;
  const float* gw = vis ? vg : tg;
  {
    const int e = t & 63, pr = t >> 6;
    float acc = 0.f;
    for (int h = pr * 256; h < (pr + 1) * 256; ++h) acc += xs[h] * gw[h * NEXP + e];
    part[pr][e] = acc;
  }
  __syncthreads();
  if (t < NEXP) {
    float a = part[0][t] + part[1][t] + part[2][t] + part[3][t];
    float s = 1.f / (1.f + expf(-a));
    sc[t] = s;
    sb[t] = s + cbias[vis * NEXP + t];
  }
  __syncthreads();
  if (t == 0) {
    int chosen[NTOP];
    unsigned long long usedm = 0ULL;
    float wsum = 0.f;
    for (int k = 0; k < NTOP; ++k) {
      float best = -1e30f; int bi = 0;
      for (int e = 0; e < NEXP; ++e) {
        if ((usedm >> e) & 1ULL) continue;
        if (sb[e] > best) { best = sb[e]; bi = e; }
      }
      usedm |= (1ULL << bi);
      chosen[k] = bi;
      wsum += sc[bi];
    }
    const float inv = 1.f / wsum;
    for (int k = 0; k < NTOP; ++k) {
      int e = chosen[k];
      int slot = vis * NEXP + e;
      int pos = atomicAdd(&counts[slot], 1);
      ptok[slot * TT + pos] = tok;
      pw[slot * TT + pos] = sc[e] * inv;
    }
  }
}

__global__ void scan_kernel(const int* __restrict__ counts, int* __restrict__ rowoff) {
  if (threadIdx.x == 0 && blockIdx.x == 0) {
    int s = 0;
    for (int i = 0; i < 128; ++i) { rowoff[i] = s; s += counts[i]; }
    rowoff[128] = s;
  }
}

template<int MODE>
__device__ inline void act_base(const int* rowoff, int slot, size_t& eb, int& stride) {
  if (MODE == 0) { eb = (size_t)rowoff[slot] * 512; stride = 512; }
  else if (MODE == 1) {
    int Rt = rowoff[64];
    eb = (size_t)Rt * 512 + (size_t)(rowoff[slot] - Rt) * 256; stride = 256;
  } else { eb = SBASE; stride = 1024; }
}

// ---------------- gate+up body: 64-col tiles (round-13 body, e/cch parameterized) -----
template<int IDIM, int MODE>
__device__ __forceinline__ void gateup_body(int cch, int eg,
    const u16* __restrict__ X,
    const float* __restrict__ WG, const float* __restrict__ WU,
    const int* __restrict__ counts, const int* __restrict__ ptok,
    const float* __restrict__ pw, const int* __restrict__ rowoff,
    u16* __restrict__ ACT,
    u16 (&sG)[2][8192], u16 (&sU)[2][8192],
    int (&toksL)[256], float (&twsL)[256]) {
  const int c0 = cch * 64;
  int cnt, mstart, mend, slot = 0;
  size_t eb; int stride;
  const float *wgp, *wup;
  if (MODE == 2) {
    cnt = TT; mstart = eg * 256; mend = mstart + 256;
    eb = SBASE; stride = 1024;
    wgp = WG; wup = WU;
  } else {
    slot = (MODE == 1 ? NEXP : 0) + eg;
    cnt = counts[slot];
    mstart = 0; mend = cnt;
    act_base<MODE>(rowoff, slot, eb, stride);
    wgp = WG + (size_t)eg * HID * IDIM;
    wup = WU + (size_t)eg * HID * IDIM;
  }
  if (mstart >= mend) return;
  const int w = threadIdx.x >> 6, lane = threadIdx.x & 63;
  const int lrow = lane & 15, loct = lane >> 4;

  for (int m0 = mstart; m0 < mend; m0 += 256) {
    {
      int gi = m0 + threadIdx.x;
      int tok = 0; float tw = 0.f;
      if (gi < cnt) {
        tok = (MODE == 2) ? gi : ptok[slot * TT + gi];
        tw  = (MODE == 2) ? 1.f : pw[slot * TT + gi];
      }
      toksL[threadIdx.x] = tok; twsL[threadIdx.x] = tw;
    }
    float4 rg[8], ru[8];
    wload64(wgp, IDIM, c0, 0, rg);
    wload64(wup, IDIM, c0, 0, ru);
    __syncthreads();
    wwrite64(rg, sG[0]);
    wwrite64(ru, sU[0]);
    const u16* xr[4];
#pragma unroll
    for (int tt = 0; tt < 4; ++tt)
      xr[tt] = X + (size_t)toksL[(w + tt * 4) * 16 + lrow] * HID;
    f32x4 aG[4][4], aU[4][4];
#pragma unroll
    for (int tt = 0; tt < 4; ++tt)
#pragma unroll
      for (int cf = 0; cf < 4; ++cf) {
        aG[tt][cf] = (f32x4){0.f,0.f,0.f,0.f};
        aU[tt][cf] = (f32x4){0.f,0.f,0.f,0.f};
      }
    __syncthreads();
    for (int c = 0; c < HID / 128; ++c) {
      const int cur = c & 1;
      if (c + 1 < HID / 128) {
        wload64(wgp, IDIM, c0, (c + 1) * 128, rg);
        wload64(wup, IDIM, c0, (c + 1) * 128, ru);
      }
#pragma unroll
      for (int ks = 0; ks < 4; ++ks) {
        short8v a[4];
#pragma unroll
        for (int tt = 0; tt < 4; ++tt)
          a[tt] = *(const short8v*)&xr[tt][c * 128 + ks * 32 + loct * 8];
        const int gbase = ((ks * 4 + loct) * 64 + lrow) * 8;
#pragma unroll
        for (int cf = 0; cf < 4; ++cf) {
          short8v bg = *(const short8v*)&sG[cur][gbase + cf * 128];
          short8v bu = *(const short8v*)&sU[cur][gbase + cf * 128];
#pragma unroll
          for (int tt = 0; tt < 4; ++tt) {
            aG[tt][cf] = mfma16(a[tt], bg, aG[tt][cf]);
            aU[tt][cf] = mfma16(a[tt], bu, aU[tt][cf]);
          }
        }
      }
      if (c + 1 < HID / 128) {
        wwrite64(rg, sG[cur ^ 1]);
        wwrite64(ru, sU[cur ^ 1]);
      }
      __syncthreads();
    }
#pragma unroll
    for (int tt = 0; tt < 4; ++tt) {
      const int ti = w + tt * 4;
#pragma unroll
      for (int i = 0; i < 4; ++i) {
        const int r = loct * 4 + i;
        const int gi = m0 + ti * 16 + r;
        if (gi < cnt) {
          const float twv = twsL[ti * 16 + r];
#pragma unroll
          for (int cf = 0; cf < 4; ++cf) {
            float g = aG[tt][cf][i], u = aU[tt][cf][i];
            float a = g / (1.f + expf(-g)) * u * twv;
            ACT[eb + (size_t)gi * stride + c0 + cf * 16 + lrow] = f2bf(a);
          }
        }
      }
    }
    __syncthreads();
  }
}

// fused: text 512 (8cch x 64e) | vision 256 (4 x 64) | shared 128 (16 x 8); 896 = 8*112
__global__ __launch_bounds__(256) void gateup_fused(const u16* __restrict__ X,
    const float* __restrict__ swg, const float* __restrict__ swu,
    const float* __restrict__ twg, const float* __restrict__ twu,
    const float* __restrict__ vwg, const float* __restrict__ vwu,
    const int* __restrict__ counts, const int* __restrict__ ptok,
    const float* __restrict__ pw, const int* __restrict__ rowoff,
    u16* __restrict__ ACT) {
  __shared__ u16 sG[2][8192], sU[2][8192];
  __shared__ int toksL[256];
  __shared__ float twsL[256];
  const int P = blockIdx.x;
  const int L = (P & 7) * 112 + (P >> 3);   // expert-contiguous per XCD (bijective)
  if (L < 512)
    gateup_body<I_T, 0>(L & 7, L >> 3, X, twg, twu, counts, ptok, pw, rowoff, ACT, sG, sU, toksL, twsL);
  else if (L < 768) {
    int l = L - 512;
    gateup_body<I_V, 1>(l & 3, l >> 2, X, vwg, vwu, counts, ptok, pw, rowoff, ACT, sG, sU, toksL, twsL);
  } else {
    int l = L - 768;
    gateup_body<I_S, 2>(l & 15, l >> 4, X, swg, swu, counts, ptok, pw, rowoff, ACT, sG, sU, toksL, twsL);
  }
}

// ---------------- down body: 64-col tiles (round-13 body, e/cch parameterized) --------
template<int KDIM, int MODE>
__device__ __forceinline__ void down_body(int cch, int eg,
    const u16* __restrict__ ACT, const float* __restrict__ WD,
    const int* __restrict__ counts, const int* __restrict__ ptok,
    const int* __restrict__ rowoff, float* __restrict__ OUT,
    u16 (&sW)[2][8192], int (&toksL)[256]) {
  const int c0 = cch * 64;
  int cnt, mstart, mend, slot = 0;
  size_t eb; int stride;
  const float* wdp;
  if (MODE == 2) {
    cnt = TT; mstart = eg * 256; mend = mstart + 256;
    eb = SBASE; stride = 1024;
    wdp = WD;
  } else {
    slot = (MODE == 1 ? NEXP : 0) + eg;
    cnt = counts[slot];
    mstart = 0; mend = cnt;
    act_base<MODE>(rowoff, slot, eb, stride);
    wdp = WD + (size_t)eg * KDIM * HID;
  }
  if (mstart >= mend) return;
  const int w = threadIdx.x >> 6, lane = threadIdx.x & 63;
  const int lrow = lane & 15, loct = lane >> 4;
  constexpr int NC = KDIM / 128;

  for (int m0 = mstart; m0 < mend; m0 += 256) {
    {
      int gi = m0 + threadIdx.x;
      int tok = 0;
      if (gi < cnt) tok = (MODE == 2) ? gi : ptok[slot * TT + gi];
      toksL[threadIdx.x] = tok;
    }
    float4 rw[8];
    wload64(wdp, HID, c0, 0, rw);
    __syncthreads();
    wwrite64(rw, sW[0]);
    const u16* ar[4];
#pragma unroll
    for (int tt = 0; tt < 4; ++tt) {
      int gi = m0 + (w + tt * 4) * 16 + lrow;
      int gc = (gi < cnt) ? gi : (cnt - 1);
      ar[tt] = ACT + eb + (size_t)gc * stride;
    }
    f32x4 acc[4][4];
#pragma unroll
    for (int tt = 0; tt < 4; ++tt)
#pragma unroll
      for (int cf = 0; cf < 4; ++cf) acc[tt][cf] = (f32x4){0.f,0.f,0.f,0.f};
    __syncthreads();
    for (int c = 0; c < NC; ++c) {
      const int cur = c & 1;
      if (c + 1 < NC) wload64(wdp, HID, c0, (c + 1) * 128, rw);
#pragma unroll
      for (int ks = 0; ks < 4; ++ks) {
        short8v a[4];
#pragma unroll
        for (int tt = 0; tt < 4; ++tt)
          a[tt] = *(const short8v*)&ar[tt][c * 128 + ks * 32 + loct * 8];
        const int gbase = ((ks * 4 + loct) * 64 + lrow) * 8;
#pragma unroll
        for (int cf = 0; cf < 4; ++cf) {
          short8v b = *(const short8v*)&sW[cur][gbase + cf * 128];
#pragma unroll
          for (int tt = 0; tt < 4; ++tt)
            acc[tt][cf] = mfma16(a[tt], b, acc[tt][cf]);
        }
      }
      if (c + 1 < NC) wwrite64(rw, sW[cur ^ 1]);
      __syncthreads();
    }
#pragma unroll
    for (int tt = 0; tt < 4; ++tt) {
      const int ti = w + tt * 4;
#pragma unroll
      for (int i = 0; i < 4; ++i) {
        const int r = loct * 4 + i;
        const int gi = m0 + ti * 16 + r;
        if (gi < cnt) {
          const int tok = toksL[ti * 16 + r];
#pragma unroll
          for (int cf = 0; cf < 4; ++cf)
            atomicAdd(&OUT[(size_t)tok * HID + c0 + cf * 16 + lrow], acc[tt][cf][i]);
        }
      }
    }
    __syncthreads();
  }
}

// fused: text 1024 (16cch x 64e) | vision 1024 | shared 128 (16 x 8); 2176 = 8*272
__global__ __launch_bounds__(256) void down_fused(const u16* __restrict__ ACT,
    const float* __restrict__ swd, const float* __restrict__ twd,
    const float* __restrict__ vwd,
    const int* __restrict__ counts, const int* __restrict__ ptok,
    const int* __restrict__ rowoff, float* __restrict__ OUT) {
  __shared__ u16 sW[2][8192];
  __shared__ int toksL[256];
  const int P = blockIdx.x;
  const int L = (P & 7) * 272 + (P >> 3);   // bijective, expert-contiguous per XCD
  if (L < 1024)
    down_body<I_T, 0>(L & 15, L >> 4, ACT, twd, counts, ptok, rowoff, OUT, sW, toksL);
  else if (L < 2048) {
    int l = L - 1024;
    down_body<I_V, 1>(l & 15, l >> 4, ACT, vwd, counts, ptok, rowoff, OUT, sW, toksL);
  } else {
    int l = L - 2048;
    down_body<I_S, 2>(l & 15, l >> 4, ACT, swd, counts, ptok, rowoff, OUT, sW, toksL);
  }
}

// ---------------- out = a + b ----------------
__global__ __launch_bounds__(256) void add2_kernel(const float* __restrict__ a,
                                                   const float* __restrict__ b,
                                                   float* __restrict__ out) {
  const size_t i = ((size_t)blockIdx.x * 256 + threadIdx.x) * 4;
  const float4 va = *(const float4*)(a + i);
  const float4 vb = *(const float4*)(b + i);
  float4 o;
  o.x = va.x + vb.x; o.y = va.y + vb.y; o.z = va.z + vb.z; o.w = va.w + vb.w;
  *(float4*)(out + i) = o;
}

extern "C" void kernel_launch(void* const* d_in, const int* in_sizes, int n_in,
                              void* d_out, int out_size, void* d_ws, size_t ws_size,
                              hipStream_t stream) {
  const float* hidden   = (const float*)d_in[0];
  const int*   positions= (const int*)d_in[1];
  const int*   vmask    = (const int*)d_in[2];
  const float* w_qkv    = (const float*)d_in[3];
  const float* w_o      = (const float*)d_in[4];
  const float* ln1      = (const float*)d_in[5];
  const float* ln2      = (const float*)d_in[6];
  const float* tgw      = (const float*)d_in[7];
  const float* vgw      = (const float*)d_in[8];
  const float* cbias    = (const float*)d_in[9];
  const float* twg      = (const float*)d_in[10];
  const float* twu      = (const float*)d_in[11];
  const float* twd      = (const float*)d_in[12];
  const float* vwg      = (const float*)d_in[13];
  const float* vwu      = (const float*)d_in[14];
  const float* vwd      = (const float*)d_in[15];
  const float* swg      = (const float*)d_in[16];
  const float* swu      = (const float*)d_in[17];
  const float* swd      = (const float*)d_in[18];
  float* out = (float*)d_out;

  char* ws = (char*)d_ws;
  size_t off = 0;
  auto alloc = [&](size_t bytes) -> void* {
    void* p = ws + off;
    off += (bytes + 255) & ~(size_t)255;
    return p;
  };
  u16*   xbh   = (u16*)alloc((size_t)TT * HID * 2);
  u16*   xbl   = (u16*)alloc((size_t)TT * HID * 2);
  float* qkv   = (float*)alloc((size_t)TT * QKVN * 4);
  u16*   aoH   = (u16*)alloc((size_t)TT * HID * 2);
  u16*   aoL   = (u16*)alloc((size_t)TT * HID * 2);
  float* hbuf  = (float*)alloc((size_t)TT * HID * 4);
  float* x2    = (float*)alloc((size_t)TT * HID * 4);
  u16*   xb2   = (u16*)alloc((size_t)TT * HID * 2);
  float* moe   = (float*)alloc((size_t)TT * HID * 4);
  u16*   ACT   = (u16*)alloc((SBASE + (size_t)TT * 1024) * 2);
  u16*   Qph   = (u16*)alloc((size_t)TT * HID * 2);
  u16*   Qpl   = (u16*)alloc((size_t)TT * HID * 2);
  u16*   Kph   = (u16*)alloc((size_t)NKVH * TT * HD * 2);
  u16*   Kpl   = (u16*)alloc((size_t)NKVH * TT * HD * 2);
  u16*   Vph   = (u16*)alloc((size_t)NKVH * TT * HD * 2);
  u16*   Vpl   = (u16*)alloc((size_t)NKVH * TT * HD * 2);
  float* Opart = (float*)alloc((size_t)NHEAD * NCHUNK * 16 * 128 * 4);
  float* Mpart = (float*)alloc((size_t)NHEAD * NCHUNK * 16 * 4);
  float* Lpart = (float*)alloc((size_t)NHEAD * NCHUNK * 16 * 4);
  int*   ctab  = (int*)alloc(NCHUNK * 4);
  int*   cstart= (int*)alloc((TT / 16) * 4);
  int*   counts= (int*)alloc(128 * 4);
  int*   rowoff= (int*)alloc(129 * 4);
  int*   ptok  = (int*)alloc((size_t)128 * TT * 4);
  float* pwgt  = (float*)alloc((size_t)128 * TT * 4);

  hipMemsetAsync(counts, 0, 128 * 4, stream);
  hipMemsetAsync(moe, 0, (size_t)TT * HID * 4, stream);

  // one-time tables (parallel, closed-form)
  chunk_setup<<<1, 128, 0, stream>>>(ctab, cstart);

  // pre-gate path, split-bf16 precision (weights streamed fp32 in-kernel)
  rmsnorm_kernel<false, true, true><<<TT, 256, 0, stream>>>(hidden, ln1, nullptr, xbh, xbl);
  dense_stream<false><<<dim3(QKVN / 64, TT / 128), 256, 0, stream>>>(xbh, xbl, w_qkv, nullptr, qkv, QKVN);
  pack_qkv<<<TT / 32, 256, 0, stream>>>(qkv, positions, Qph, Qpl, Kph, Kpl, Vph, Vpl);
  attn_part<<<dim3(NCHUNK, NKVH), 256, 0, stream>>>(Qph, Qpl, Kph, Kpl, Vph, Vpl, ctab, Opart, Mpart, Lpart);
  attn_combine<<<dim3(TT / 16, NHEAD), 256, 0, stream>>>(Opart, Mpart, Lpart, cstart, aoH, aoL);
  dense_stream<true><<<dim3(HID / 64, TT / 128), 256, 0, stream>>>(aoH, aoL, w_o, hidden, hbuf, HID);
  rmsnorm_kernel<true, true, false><<<TT, 256, 0, stream>>>(hbuf, ln2, x2, xb2, nullptr);
  gate_kernel<<<TT, 256, 0, stream>>>(x2, vmask, tgw, vgw, cbias, counts, ptok, pwgt);
  scan_kernel<<<1, 64, 0, stream>>>(counts, rowoff);

  // MoE + shared MLP: fused streaming kernels (round-14 best: fused gateup + fused down)
  gateup_fused<<<896, 256, 0, stream>>>(xb2, swg, swu, twg, twu, vwg, vwu,
                                        counts, ptok, pwgt, rowoff, ACT);
  down_fused<<<2176, 256, 0, stream>>>(ACT, swd, twd, vwd, counts, ptok, rowoff, moe);

  add2_kernel<<<(TT * HID) / 1024, 256, 0, stream>>>(hbuf, moe, out);
}